// Round 2
// baseline (213.751 us; speedup 1.0000x reference)
//
#include <hip/hip_runtime.h>
#include <hip/hip_bf16.h>
#include <math.h>

// Problem constants
#define SPAN 845            // 5 * 169 = 13*13*5 cells per channel span
#define PLANE 169           // 13*13
#define NCH3 63             // 21 joints * 3 coords
#define NCHIN 64            // 63 uvd channels + 1 conf channel
#define NUM_CLASS 45
#define NUM_SEG 5

__device__ __forceinline__ float sigmoidf_(float x) {
    return 1.0f / (1.0f + expf(-x));
}

// Permuted-value gather from the block's LDS tile.
// p: position within the block's output group (c = p/845 channel-in-group,
// t = p%845 with t = ij*5 + d; source element = c*845 + d*169 + ij).
// Sigmoid applies only to global channels 0..2 (group g==0, p < 3*SPAN).
__device__ __forceinline__ float permval(const float* lds, int p, int g) {
    const int c  = p / SPAN;
    const int t  = p - c * SPAN;
    const int ij = t / 5;
    const int d  = t - ij * 5;
    float v = lds[c * SPAN + d * PLANE + ij];
    if (g == 0 && p < 3 * SPAN) v = sigmoidf_(v);
    return v;
}

// Kernel 1: permute + sigmoid(joint0 channels) + per-sample argmax of conf.
// Grid: bs*16 blocks. Block (b, g): groups 0..14 -> channels 4g..4g+3;
// group 15 -> channels 60..62 (permute) + channel 63 (conf -> argmax).
__global__ __launch_bounds__(256) void permute_argmax_kernel(
        const float* __restrict__ in,       // (bs*64, 845)
        float* __restrict__ uvd_out,        // (bs*63, 845)
        float* __restrict__ top_out)        // (bs,) float(index)
{
    const int blk = blockIdx.x;
    const int b = blk >> 4;
    const int g = blk & 15;
    const int tid = threadIdx.x;

    __shared__ float lds[4 * SPAN];
    __shared__ float wv[4];
    __shared__ int   wi[4];

    // Coalesced float4 load of 4 contiguous channel spans (16B-aligned base:
    // (b*64 + 4g)*845 is a multiple of 4 floats).
    const float4* in4 = (const float4*)in;
    const int base4 = (b * 16 + g) * SPAN;
    float4* lds4 = (float4*)lds;
    for (int f = tid; f < SPAN; f += 256) {
        lds4[f] = in4[base4 + f];
    }
    __syncthreads();

    // Vectorized permuted store of the group's contiguous output region.
    const int size  = (g == 15) ? 3 * SPAN : 4 * SPAN;     // floats in group
    const int obase = (b * NCH3 + g * 4) * SPAN;           // group base (floats)
    const int h     = (4 - (obase & 3)) & 3;               // scalar head count

    if (tid < h && tid < size) {
        uvd_out[obase + tid] = permval(lds, tid, g);
    }
    const int nbody = (size - h) >> 2;                     // # of float4 stores
    float4* out4 = (float4*)(uvd_out + obase + h);
    for (int q = tid; q < nbody; q += 256) {
        const int p0 = h + q * 4;
        float4 v;
        v.x = permval(lds, p0 + 0, g);
        v.y = permval(lds, p0 + 1, g);
        v.z = permval(lds, p0 + 2, g);
        v.w = permval(lds, p0 + 3, g);
        out4[q] = v;
    }
    const int tstart = h + nbody * 4;
    const int ntail  = size - tstart;                      // 0..3
    if (tid < ntail) {
        uvd_out[obase + tstart + tid] = permval(lds, tstart + tid, g);
    }

    if (g == 15) {
        // Argmax over conf logits (sigmoid monotonic -> raw argmax).
        // Tie-break: lowest flat index t = ij*5+d (matches top_k stability).
        const float* conf = &lds[3 * SPAN];
        float bv = -INFINITY;
        int   bi = SPAN;
        for (int t = tid; t < SPAN; t += 256) {
            const int ij = t / 5;
            const int d  = t - ij * 5;
            const float v = conf[d * PLANE + ij];
            if (v > bv || (v == bv && t < bi)) { bv = v; bi = t; }
        }
        for (int off = 32; off > 0; off >>= 1) {
            const float ov = __shfl_down(bv, off);
            const int   oi = __shfl_down(bi, off);
            if (ov > bv || (ov == bv && oi < bi)) { bv = ov; bi = oi; }
        }
        if ((tid & 63) == 0) { wv[tid >> 6] = bv; wi[tid >> 6] = bi; }
        __syncthreads();
        if (tid == 0) {
            for (int w = 1; w < 4; ++w) {
                if (wv[w] > bv || (wv[w] == bv && wi[w] < bi)) { bv = wv[w]; bi = wi[w]; }
            }
            top_out[b] = (float)bi;
        }
    }
}

// Kernel 2: per clip (bs/5), average the 5 segments' best-cell uvd vectors
// (read from the already-permuted uvd_out: sigmoid applied, index = t), then
// apply the linear FC (mean commutes with the linear layer).
__global__ __launch_bounds__(64) void fc_consensus_kernel(
        const float* __restrict__ uvd_out,  // (bs*63, 845)
        const float* __restrict__ top_out,  // (bs,) float(index)
        const float* __restrict__ fc_w,     // (45, 63)
        const float* __restrict__ fc_b,     // (45,)
        float* __restrict__ out3)           // (bs/5, 45)
{
    const int clip = blockIdx.x;
    const int tid = threadIdx.x;
    __shared__ float avg[NCH3];

    if (tid < NCH3) {
        float s = 0.0f;
        for (int seg = 0; seg < NUM_SEG; ++seg) {
            const int b = clip * NUM_SEG + seg;
            const int t = (int)top_out[b];
            s += uvd_out[((size_t)b * NCH3 + tid) * SPAN + t];
        }
        avg[tid] = s * (1.0f / NUM_SEG);
    }
    __syncthreads();
    if (tid < NUM_CLASS) {
        float acc = fc_b[tid];
        #pragma unroll
        for (int k = 0; k < NCH3; ++k) acc += avg[k] * fc_w[tid * NCH3 + k];
        out3[clip * NUM_CLASS + tid] = acc;
    }
}

extern "C" void kernel_launch(void* const* d_in, const int* in_sizes, int n_in,
                              void* d_out, int out_size, void* d_ws, size_t ws_size,
                              hipStream_t stream) {
    const float* base_out = (const float*)d_in[0];
    const float* fc_w     = (const float*)d_in[1];
    const float* fc_b     = (const float*)d_in[2];

    const int bs = in_sizes[0] / (NCHIN * SPAN);   // 2560
    const int clips = bs / NUM_SEG;                // 512

    float* uvd_out = (float*)d_out;                        // bs*63*845
    float* top_out = uvd_out + (size_t)bs * NCH3 * SPAN;   // bs
    float* out3    = top_out + bs;                         // clips*45

    permute_argmax_kernel<<<bs * 16, 256, 0, stream>>>(base_out, uvd_out, top_out);
    fc_consensus_kernel<<<clips, 64, 0, stream>>>(uvd_out, top_out, fc_w, fc_b, out3);
}